// Round 8
// baseline (243.028 us; speedup 1.0000x reference)
//
#include <hip/hip_runtime.h>

#define NBSH 7                  // 128 nodes per dst-bucket
#define NBNODES 128
#define MAXB 1024               // static LDS bound on bucket count
#define CHUNK 16384             // edges per coarse block
#define CTHREADS 1024
#define SRCMASK 0x1FFFF         // n_nodes < 2^17

typedef unsigned short ushort_t;
typedef unsigned int uint_t;

__device__ __forceinline__ ushort_t f32_to_bf16_rne(float f) {
    const uint_t u = __float_as_uint(f);
    return (ushort_t)((u + 0x7FFFu + ((u >> 16) & 1u)) >> 16);
}

// ---------------------------------------------------------------------------
// h = feat @ W + bias -> bf16. Software-pipelined: prefetch tile t+1 into
// registers while computing tile t from LDS. 16 rows/tile (one float4 per
// thread per tile, fully coalesced), 4 rows/thread -> 4 independent FMA
// chains. One barrier per iteration (double buffer).
// ---------------------------------------------------------------------------
__global__ __launch_bounds__(256) void gat_linear_kernel(
    const float* __restrict__ feat, const float* __restrict__ W,
    const float* __restrict__ bias, ushort_t* __restrict__ hbf, int n_nodes)
{
    const int c = threadIdx.x & 63;   // output column == lane
    const int g = threadIdx.x >> 6;   // wave id 0..3

    float w[64];
    #pragma unroll
    for (int k = 0; k < 64; ++k) w[k] = W[k * 64 + c];
    const float b = bias[c];

    __shared__ float sf[2][16][64];   // 8 KB double buffer

    const int lrow = threadIdx.x >> 4;        // 0..15 (staged row)
    const int lcol = (threadIdx.x & 15) * 4;  // 0..60 (float4 col)
    const int step = gridDim.x * 16;

    int base = blockIdx.x * 16;
    if (base >= n_nodes) return;

    // prologue: load tile 0
    float4 p = make_float4(0.f, 0.f, 0.f, 0.f);
    {
        const int row = base + lrow;
        if (row < n_nodes)
            p = *reinterpret_cast<const float4*>(&feat[(size_t)row * 64 + lcol]);
    }

    int buf = 0;
    for (; base < n_nodes; base += step) {
        *reinterpret_cast<float4*>(&sf[buf][lrow][lcol]) = p;
        __syncthreads();

        // prefetch next tile while computing this one
        const int nbase = base + step;
        if (nbase < n_nodes) {
            const int row = nbase + lrow;
            p = (row < n_nodes)
                ? *reinterpret_cast<const float4*>(&feat[(size_t)row * 64 + lcol])
                : make_float4(0.f, 0.f, 0.f, 0.f);
        }

        float acc0 = b, acc1 = b, acc2 = b, acc3 = b;
        #pragma unroll
        for (int k = 0; k < 64; k += 4) {
            const float4 f0 = *reinterpret_cast<const float4*>(&sf[buf][g][k]);
            const float4 f1 = *reinterpret_cast<const float4*>(&sf[buf][g + 4][k]);
            const float4 f2 = *reinterpret_cast<const float4*>(&sf[buf][g + 8][k]);
            const float4 f3 = *reinterpret_cast<const float4*>(&sf[buf][g + 12][k]);
            acc0 = fmaf(f0.x, w[k + 0], acc0);
            acc1 = fmaf(f1.x, w[k + 0], acc1);
            acc2 = fmaf(f2.x, w[k + 0], acc2);
            acc3 = fmaf(f3.x, w[k + 0], acc3);
            acc0 = fmaf(f0.y, w[k + 1], acc0);
            acc1 = fmaf(f1.y, w[k + 1], acc1);
            acc2 = fmaf(f2.y, w[k + 1], acc2);
            acc3 = fmaf(f3.y, w[k + 1], acc3);
            acc0 = fmaf(f0.z, w[k + 2], acc0);
            acc1 = fmaf(f1.z, w[k + 2], acc1);
            acc2 = fmaf(f2.z, w[k + 2], acc2);
            acc3 = fmaf(f3.z, w[k + 2], acc3);
            acc0 = fmaf(f0.w, w[k + 3], acc0);
            acc1 = fmaf(f1.w, w[k + 3], acc1);
            acc2 = fmaf(f2.w, w[k + 3], acc2);
            acc3 = fmaf(f3.w, w[k + 3], acc3);
        }
        const int r0 = base + g;
        if (r0 < n_nodes)      hbf[(size_t)r0 * 64 + c]        = f32_to_bf16_rne(acc0);
        if (r0 + 4 < n_nodes)  hbf[(size_t)(r0 + 4) * 64 + c]  = f32_to_bf16_rne(acc1);
        if (r0 + 8 < n_nodes)  hbf[(size_t)(r0 + 8) * 64 + c]  = f32_to_bf16_rne(acc2);
        if (r0 + 12 < n_nodes) hbf[(size_t)(r0 + 12) * 64 + c] = f32_to_bf16_rne(acc3);

        buf ^= 1;
        __syncthreads();
    }
}

// ---------------------------------------------------------------------------
// Coarse bucket totals: per-block LDS histogram -> global atomic add.
// ---------------------------------------------------------------------------
__global__ __launch_bounds__(CTHREADS) void coarse_hist_kernel(
    const int* __restrict__ dst, int* __restrict__ btot, int n_edges, int nbuck)
{
    __shared__ int cnt[MAXB];
    for (int i = threadIdx.x; i < nbuck; i += CTHREADS) cnt[i] = 0;
    __syncthreads();
    const int base = blockIdx.x * CHUNK;
    for (int i = threadIdx.x; i < CHUNK; i += CTHREADS) {
        const int e = base + i;
        if (e < n_edges) atomicAdd(&cnt[dst[e] >> NBSH], 1);
    }
    __syncthreads();
    for (int q = threadIdx.x; q < nbuck; q += CTHREADS) {
        const int c = cnt[q];
        if (c) atomicAdd(&btot[q], c);
    }
}

// Single-block exclusive scan of bucket totals -> bb[0..nbuck].
__global__ __launch_bounds__(1024) void bucket_scan_kernel(
    const int* __restrict__ btot, int* __restrict__ bb, int nbuck)
{
    __shared__ int s[1024];
    const int t = threadIdx.x;
    const int v = (t < nbuck) ? btot[t] : 0;
    s[t] = v;
    __syncthreads();
    for (int off = 1; off < 1024; off <<= 1) {
        const int y = (t >= off) ? s[t - off] : 0;
        __syncthreads();
        s[t] += y;
        __syncthreads();
    }
    if (t < nbuck) bb[t] = s[t] - v;
    if (t == nbuck - 1) bb[nbuck] = s[t];   // total == n_edges
}

// ---------------------------------------------------------------------------
// Coarse scatter: block reserves one run per bucket (single global atomicAdd),
// writes its edges for that bucket consecutively -> L2 write merging.
// pkA word0 = src | dlow<<17 ; word1 = att bits.
// ---------------------------------------------------------------------------
__global__ __launch_bounds__(CTHREADS) void coarse_scatter_kernel(
    const int* __restrict__ src, const int* __restrict__ dst,
    const float* __restrict__ att, const int* __restrict__ bb,
    int* __restrict__ gcur, int2* __restrict__ pkA, int n_edges, int nbuck)
{
    __shared__ int cnt[MAXB];
    __shared__ int rbase[MAXB];
    for (int i = threadIdx.x; i < nbuck; i += CTHREADS) cnt[i] = 0;
    __syncthreads();

    const int base = blockIdx.x * CHUNK;
    for (int i = threadIdx.x; i < CHUNK; i += CTHREADS) {
        const int e = base + i;
        if (e < n_edges) atomicAdd(&cnt[dst[e] >> NBSH], 1);
    }
    __syncthreads();

    for (int q = threadIdx.x; q < nbuck; q += CTHREADS) {
        const int c = cnt[q];
        rbase[q] = c ? (bb[q] + atomicAdd(&gcur[q], c)) : 0;
        cnt[q] = 0;                       // reuse as local cursor
    }
    __syncthreads();

    for (int i = threadIdx.x; i < CHUNK; i += CTHREADS) {
        const int e = base + i;
        if (e < n_edges) {
            const int d = dst[e];
            const int q = d >> NBSH;
            const int local = atomicAdd(&cnt[q], 1);
            pkA[rbase[q] + local] =
                make_int2(src[e] | ((d & (NBNODES - 1)) << 17),
                          __float_as_int(att[e]));
        }
    }
}

// ---------------------------------------------------------------------------
// Fine sort: one block per bucket, LDS counting sort by node-low bits;
// emits node-grouped pkB + per-node offsets.
// ---------------------------------------------------------------------------
__global__ __launch_bounds__(256) void fine_sort_kernel(
    const int2* __restrict__ pkA, const int* __restrict__ bb,
    int2* __restrict__ pkB, int* __restrict__ offs,
    int n_nodes, int n_edges, int nbuck)
{
    __shared__ int cnt[NBNODES];
    __shared__ int sbase[NBNODES];
    const int q = blockIdx.x;
    const int beg = bb[q], end = bb[q + 1];
    const int t = threadIdx.x;

    if (t < NBNODES) cnt[t] = 0;
    __syncthreads();

    for (int i = beg + t; i < end; i += 256)
        atomicAdd(&cnt[(unsigned)pkA[i].x >> 17], 1);
    __syncthreads();

    int v = 0;
    if (t < NBNODES) { v = cnt[t]; sbase[t] = v; }
    __syncthreads();
    for (int off = 1; off < NBNODES; off <<= 1) {
        int y = 0;
        if (t < NBNODES && t >= off) y = sbase[t - off];
        __syncthreads();
        if (t < NBNODES) sbase[t] += y;
        __syncthreads();
    }
    if (t < NBNODES) {
        sbase[t] += beg - v;
        const int node = (q << NBSH) + t;
        if (node < n_nodes) offs[node] = sbase[t];
        cnt[t] = 0;
    }
    if (q == 0 && t == 0) offs[n_nodes] = n_edges;
    __syncthreads();

    for (int i = beg + t; i < end; i += 256) {
        const int2 w = pkA[i];
        const int dlow = (unsigned)w.x >> 17;
        const int local = atomicAdd(&cnt[dlow], 1);
        pkB[sbase[dlow] + local] = make_int2(w.x & SRCMASK, w.y);
    }
}

// ---------------------------------------------------------------------------
// Aggregate (proven, round-7): quarter-wave per node; each lane gathers 8B
// (4 bf16) of the source row; row stride = 16 uint2.
// ---------------------------------------------------------------------------
__global__ __launch_bounds__(256) void gat_aggregate_kernel(
    const ushort_t* __restrict__ hbf, const int* __restrict__ offs,
    const int2* __restrict__ pk, float* __restrict__ out, int n_nodes)
{
    const int q = (blockIdx.x * 256 + (int)threadIdx.x) >> 4;
    const int l = threadIdx.x & 15;
    if (q >= n_nodes) return;

    const int beg = offs[q], end = offs[q + 1];
    const uint2* __restrict__ h2 = reinterpret_cast<const uint2*>(hbf);

    float4 acc = make_float4(0.f, 0.f, 0.f, 0.f);
    int j = beg;
    for (; j + 2 <= end; j += 2) {
        const int2 p0 = pk[j];
        const int2 p1 = pk[j + 1];
        const uint2 u0 = h2[(size_t)p0.x * 16 + l];
        const uint2 u1 = h2[(size_t)p1.x * 16 + l];
        const float a0 = __int_as_float(p0.y);
        const float a1 = __int_as_float(p1.y);
        acc.x = fmaf(__uint_as_float(u0.x << 16), a0, acc.x);
        acc.y = fmaf(__uint_as_float(u0.x & 0xFFFF0000u), a0, acc.y);
        acc.z = fmaf(__uint_as_float(u0.y << 16), a0, acc.z);
        acc.w = fmaf(__uint_as_float(u0.y & 0xFFFF0000u), a0, acc.w);
        acc.x = fmaf(__uint_as_float(u1.x << 16), a1, acc.x);
        acc.y = fmaf(__uint_as_float(u1.x & 0xFFFF0000u), a1, acc.y);
        acc.z = fmaf(__uint_as_float(u1.y << 16), a1, acc.z);
        acc.w = fmaf(__uint_as_float(u1.y & 0xFFFF0000u), a1, acc.w);
    }
    if (j < end) {
        const int2 p0 = pk[j];
        const uint2 u0 = h2[(size_t)p0.x * 16 + l];
        const float a0 = __int_as_float(p0.y);
        acc.x = fmaf(__uint_as_float(u0.x << 16), a0, acc.x);
        acc.y = fmaf(__uint_as_float(u0.x & 0xFFFF0000u), a0, acc.y);
        acc.z = fmaf(__uint_as_float(u0.y << 16), a0, acc.z);
        acc.w = fmaf(__uint_as_float(u0.y & 0xFFFF0000u), a0, acc.w);
    }
    reinterpret_cast<float4*>(out)[(size_t)q * 16 + l] = acc;
}

extern "C" void kernel_launch(void* const* d_in, const int* in_sizes, int n_in,
                              void* d_out, int out_size, void* d_ws, size_t ws_size,
                              hipStream_t stream) {
    const float* feat = (const float*)d_in[0];   // [N,64]
    const float* att  = (const float*)d_in[1];   // [E,1]
    const int*   src  = (const int*)d_in[2];     // [E]
    const int*   dst  = (const int*)d_in[3];     // [E]
    const float* W    = (const float*)d_in[4];   // [64,64]
    const float* bias = (const float*)d_in[5];   // [64]
    float* out = (float*)d_out;                  // [N,64]

    const int n_nodes = in_sizes[0] / 64;        // 100000 (< 2^17)
    const int n_edges = in_sizes[2];             // 1.6M
    const int nbuck   = (n_nodes + NBNODES - 1) >> NBSH;   // 782
    const int cblocks = (n_edges + CHUNK - 1) / CHUNK;     // 98

    // Workspace (~26.2 MB):
    //   [0, 12.8M): union { pkA int2[E] (dead after fine_sort) ;
    //                       hbf ushort[N*64] (written by linear AFTER fine_sort) }
    //   [12.8M, 25.6M): pkB int2[E]
    //   then offs int[N+1], btot[MAXB], gcur[MAXB], bb[nbuck+1]
    char* ws = (char*)d_ws;
    ushort_t* hbf = (ushort_t*)ws;
    int2*  pkA  = (int2*)ws;
    int2*  pkB  = (int2*)(ws + (size_t)n_edges * sizeof(int2));
    int*   offs = (int*)(pkB + n_edges);
    int*   btot = offs + (n_nodes + 1);
    int*   gcur = btot + MAXB;
    int*   bb   = gcur + MAXB;

    hipMemsetAsync(btot, 0, 2 * MAXB * sizeof(int), stream);  // btot + gcur

    coarse_hist_kernel<<<cblocks, CTHREADS, 0, stream>>>(dst, btot, n_edges, nbuck);
    bucket_scan_kernel<<<1, 1024, 0, stream>>>(btot, bb, nbuck);
    coarse_scatter_kernel<<<cblocks, CTHREADS, 0, stream>>>(src, dst, att, bb,
                                                            gcur, pkA, n_edges, nbuck);
    fine_sort_kernel<<<nbuck, 256, 0, stream>>>(pkA, bb, pkB, offs,
                                                n_nodes, n_edges, nbuck);
    // linear AFTER fine_sort: hbf overwrites the dead pkA region.
    gat_linear_kernel<<<1024, 256, 0, stream>>>(feat, W, bias, hbf, n_nodes);

    const int node_qblocks = (n_nodes * 16 + 255) / 256;
    gat_aggregate_kernel<<<node_qblocks, 256, 0, stream>>>(hbf, offs, pkB, out, n_nodes);
}

// Round 10
// 192.918 us; speedup vs baseline: 1.2597x; 1.2597x over previous
//
#include <hip/hip_runtime.h>

#define NBSH 7                  // 128 nodes per dst-bucket
#define NBNODES 128
#define MAXB 1024               // static LDS bound on bucket count
#define CHUNK 16384             // edges per coarse block
#define CTHREADS 1024
#define SRCMASK 0x1FFFF         // n_nodes < 2^17

typedef unsigned short ushort_t;
typedef unsigned int uint_t;
typedef __attribute__((ext_vector_type(8))) short bf16x8;
typedef __attribute__((ext_vector_type(4))) float f32x4;

__device__ __forceinline__ ushort_t f32_to_bf16_rne(float f) {
    const uint_t u = __float_as_uint(f);
    return (ushort_t)((u + 0x7FFFu + ((u >> 16) & 1u)) >> 16);
}

// ---------------------------------------------------------------------------
// h = feat @ W + bias -> bf16, via MFMA. One wave per 16-row tile.
// A-frag: lane holds feat[r0 + (lane&15)][32km + 8*(lane>>4) + j], j=0..7
// B-frag: lane holds W[32km + 8*(lane>>4) + j][16ct + (lane&15)] (from LDS W^T)
// D: reg r -> row r0 + 4*(lane>>4) + r, col 16ct + (lane&15)   [m89/m97 layout]
// No per-tile LDS, no per-tile barriers; W^T staged once per block.
// ---------------------------------------------------------------------------
__global__ __launch_bounds__(256) void gat_linear_mfma(
    const float* __restrict__ feat, const float* __restrict__ W,
    const float* __restrict__ bias, ushort_t* __restrict__ hbf, int n_nodes)
{
    __shared__ ushort_t sWt[64][72];   // W^T bf16, 144B rows (16B aligned)
    const int tid = threadIdx.x;

    for (int i = tid; i < 64 * 64; i += 256) {
        const int k = i >> 6, c = i & 63;
        sWt[c][k] = f32_to_bf16_rne(W[i]);      // W row-major [k][c]
    }
    __syncthreads();

    const int lane = tid & 63;
    const int p = lane & 15;        // A row-in-tile / B,D column-in-ct
    const int q = lane >> 4;        // k-chunk / D row-group

    bf16x8 wf[4][2];
    float bv[4];
    #pragma unroll
    for (int ct = 0; ct < 4; ++ct) {
        #pragma unroll
        for (int km = 0; km < 2; ++km)
            wf[ct][km] = *reinterpret_cast<const bf16x8*>(&sWt[16 * ct + p][32 * km + 8 * q]);
        bv[ct] = bias[16 * ct + p];
    }

    const int wid = blockIdx.x * 4 + (tid >> 6);
    const int nwaves = gridDim.x * 4;
    const int ntiles = (n_nodes + 15) >> 4;

    for (int t = wid; t < ntiles; t += nwaves) {
        const int r0 = t << 4;
        const int rowA = min(r0 + p, n_nodes - 1);   // clamped (stores guarded)
        const float* __restrict__ fr = feat + (size_t)rowA * 64;

        f32x4 acc[4];
        #pragma unroll
        for (int ct = 0; ct < 4; ++ct)
            acc[ct] = (f32x4){bv[ct], bv[ct], bv[ct], bv[ct]};

        #pragma unroll
        for (int km = 0; km < 2; ++km) {
            const float4 fA = *reinterpret_cast<const float4*>(fr + 32 * km + 8 * q);
            const float4 fB = *reinterpret_cast<const float4*>(fr + 32 * km + 8 * q + 4);
            bf16x8 a;
            a[0] = (short)f32_to_bf16_rne(fA.x);
            a[1] = (short)f32_to_bf16_rne(fA.y);
            a[2] = (short)f32_to_bf16_rne(fA.z);
            a[3] = (short)f32_to_bf16_rne(fA.w);
            a[4] = (short)f32_to_bf16_rne(fB.x);
            a[5] = (short)f32_to_bf16_rne(fB.y);
            a[6] = (short)f32_to_bf16_rne(fB.z);
            a[7] = (short)f32_to_bf16_rne(fB.w);
            #pragma unroll
            for (int ct = 0; ct < 4; ++ct)
                acc[ct] = __builtin_amdgcn_mfma_f32_16x16x32_bf16(a, wf[ct][km], acc[ct], 0, 0, 0);
        }

        #pragma unroll
        for (int ct = 0; ct < 4; ++ct) {
            #pragma unroll
            for (int r = 0; r < 4; ++r) {
                const int row = r0 + 4 * q + r;
                if (row < n_nodes)
                    hbf[(size_t)row * 64 + 16 * ct + p] = f32_to_bf16_rne(acc[ct][r]);
            }
        }
    }
}

// ---------------------------------------------------------------------------
// Coarse bucket totals: per-block LDS histogram -> global atomic add.
// ---------------------------------------------------------------------------
__global__ __launch_bounds__(CTHREADS) void coarse_hist_kernel(
    const int* __restrict__ dst, int* __restrict__ btot, int n_edges, int nbuck)
{
    __shared__ int cnt[MAXB];
    for (int i = threadIdx.x; i < nbuck; i += CTHREADS) cnt[i] = 0;
    __syncthreads();
    const int base = blockIdx.x * CHUNK;
    for (int i = threadIdx.x; i < CHUNK; i += CTHREADS) {
        const int e = base + i;
        if (e < n_edges) atomicAdd(&cnt[dst[e] >> NBSH], 1);
    }
    __syncthreads();
    for (int q = threadIdx.x; q < nbuck; q += CTHREADS) {
        const int c = cnt[q];
        if (c) atomicAdd(&btot[q], c);
    }
}

// Single-block exclusive scan of bucket totals -> bb[0..nbuck].
__global__ __launch_bounds__(1024) void bucket_scan_kernel(
    const int* __restrict__ btot, int* __restrict__ bb, int nbuck)
{
    __shared__ int s[1024];
    const int t = threadIdx.x;
    const int v = (t < nbuck) ? btot[t] : 0;
    s[t] = v;
    __syncthreads();
    for (int off = 1; off < 1024; off <<= 1) {
        const int y = (t >= off) ? s[t - off] : 0;
        __syncthreads();
        s[t] += y;
        __syncthreads();
    }
    if (t < nbuck) bb[t] = s[t] - v;
    if (t == nbuck - 1) bb[nbuck] = s[t];   // total == n_edges
}

// ---------------------------------------------------------------------------
// Coarse scatter: block reserves one run per bucket (single global atomicAdd),
// writes its edges for that bucket consecutively -> L2 write merging.
// pkA word0 = src | dlow<<17 ; word1 = att bits.
// ---------------------------------------------------------------------------
__global__ __launch_bounds__(CTHREADS) void coarse_scatter_kernel(
    const int* __restrict__ src, const int* __restrict__ dst,
    const float* __restrict__ att, const int* __restrict__ bb,
    int* __restrict__ gcur, int2* __restrict__ pkA, int n_edges, int nbuck)
{
    __shared__ int cnt[MAXB];
    __shared__ int rbase[MAXB];
    for (int i = threadIdx.x; i < nbuck; i += CTHREADS) cnt[i] = 0;
    __syncthreads();

    const int base = blockIdx.x * CHUNK;
    for (int i = threadIdx.x; i < CHUNK; i += CTHREADS) {
        const int e = base + i;
        if (e < n_edges) atomicAdd(&cnt[dst[e] >> NBSH], 1);
    }
    __syncthreads();

    for (int q = threadIdx.x; q < nbuck; q += CTHREADS) {
        const int c = cnt[q];
        rbase[q] = c ? (bb[q] + atomicAdd(&gcur[q], c)) : 0;
        cnt[q] = 0;                       // reuse as local cursor
    }
    __syncthreads();

    for (int i = threadIdx.x; i < CHUNK; i += CTHREADS) {
        const int e = base + i;
        if (e < n_edges) {
            const int d = dst[e];
            const int q = d >> NBSH;
            const int local = atomicAdd(&cnt[q], 1);
            pkA[rbase[q] + local] =
                make_int2(src[e] | ((d & (NBNODES - 1)) << 17),
                          __float_as_int(att[e]));
        }
    }
}

// ---------------------------------------------------------------------------
// Fine sort: one block per bucket, LDS counting sort by node-low bits;
// emits node-grouped pkB + per-node offsets.
// ---------------------------------------------------------------------------
__global__ __launch_bounds__(256) void fine_sort_kernel(
    const int2* __restrict__ pkA, const int* __restrict__ bb,
    int2* __restrict__ pkB, int* __restrict__ offs,
    int n_nodes, int n_edges, int nbuck)
{
    __shared__ int cnt[NBNODES];
    __shared__ int sbase[NBNODES];
    const int q = blockIdx.x;
    const int beg = bb[q], end = bb[q + 1];
    const int t = threadIdx.x;

    if (t < NBNODES) cnt[t] = 0;
    __syncthreads();

    for (int i = beg + t; i < end; i += 256)
        atomicAdd(&cnt[(unsigned)pkA[i].x >> 17], 1);
    __syncthreads();

    int v = 0;
    if (t < NBNODES) { v = cnt[t]; sbase[t] = v; }
    __syncthreads();
    for (int off = 1; off < NBNODES; off <<= 1) {
        int y = 0;
        if (t < NBNODES && t >= off) y = sbase[t - off];
        __syncthreads();
        if (t < NBNODES) sbase[t] += y;
        __syncthreads();
    }
    if (t < NBNODES) {
        sbase[t] += beg - v;
        const int node = (q << NBSH) + t;
        if (node < n_nodes) offs[node] = sbase[t];
        cnt[t] = 0;
    }
    if (q == 0 && t == 0) offs[n_nodes] = n_edges;
    __syncthreads();

    for (int i = beg + t; i < end; i += 256) {
        const int2 w = pkA[i];
        const int dlow = (unsigned)w.x >> 17;
        const int local = atomicAdd(&cnt[dlow], 1);
        pkB[sbase[dlow] + local] = make_int2(w.x & SRCMASK, w.y);
    }
}

// ---------------------------------------------------------------------------
// Aggregate (proven): quarter-wave per node; each lane gathers 8B (4 bf16)
// of the source row; row stride = 16 uint2.
// ---------------------------------------------------------------------------
__global__ __launch_bounds__(256) void gat_aggregate_kernel(
    const ushort_t* __restrict__ hbf, const int* __restrict__ offs,
    const int2* __restrict__ pk, float* __restrict__ out, int n_nodes)
{
    const int q = (blockIdx.x * 256 + (int)threadIdx.x) >> 4;
    const int l = threadIdx.x & 15;
    if (q >= n_nodes) return;

    const int beg = offs[q], end = offs[q + 1];
    const uint2* __restrict__ h2 = reinterpret_cast<const uint2*>(hbf);

    float4 acc = make_float4(0.f, 0.f, 0.f, 0.f);
    int j = beg;
    for (; j + 2 <= end; j += 2) {
        const int2 p0 = pk[j];
        const int2 p1 = pk[j + 1];
        const uint2 u0 = h2[(size_t)p0.x * 16 + l];
        const uint2 u1 = h2[(size_t)p1.x * 16 + l];
        const float a0 = __int_as_float(p0.y);
        const float a1 = __int_as_float(p1.y);
        acc.x = fmaf(__uint_as_float(u0.x << 16), a0, acc.x);
        acc.y = fmaf(__uint_as_float(u0.x & 0xFFFF0000u), a0, acc.y);
        acc.z = fmaf(__uint_as_float(u0.y << 16), a0, acc.z);
        acc.w = fmaf(__uint_as_float(u0.y & 0xFFFF0000u), a0, acc.w);
        acc.x = fmaf(__uint_as_float(u1.x << 16), a1, acc.x);
        acc.y = fmaf(__uint_as_float(u1.x & 0xFFFF0000u), a1, acc.y);
        acc.z = fmaf(__uint_as_float(u1.y << 16), a1, acc.z);
        acc.w = fmaf(__uint_as_float(u1.y & 0xFFFF0000u), a1, acc.w);
    }
    if (j < end) {
        const int2 p0 = pk[j];
        const uint2 u0 = h2[(size_t)p0.x * 16 + l];
        const float a0 = __int_as_float(p0.y);
        acc.x = fmaf(__uint_as_float(u0.x << 16), a0, acc.x);
        acc.y = fmaf(__uint_as_float(u0.x & 0xFFFF0000u), a0, acc.y);
        acc.z = fmaf(__uint_as_float(u0.y << 16), a0, acc.z);
        acc.w = fmaf(__uint_as_float(u0.y & 0xFFFF0000u), a0, acc.w);
    }
    reinterpret_cast<float4*>(out)[(size_t)q * 16 + l] = acc;
}

extern "C" void kernel_launch(void* const* d_in, const int* in_sizes, int n_in,
                              void* d_out, int out_size, void* d_ws, size_t ws_size,
                              hipStream_t stream) {
    const float* feat = (const float*)d_in[0];   // [N,64]
    const float* att  = (const float*)d_in[1];   // [E,1]
    const int*   src  = (const int*)d_in[2];     // [E]
    const int*   dst  = (const int*)d_in[3];     // [E]
    const float* W    = (const float*)d_in[4];   // [64,64]
    const float* bias = (const float*)d_in[5];   // [64]
    float* out = (float*)d_out;                  // [N,64]

    const int n_nodes = in_sizes[0] / 64;        // 100000 (< 2^17)
    const int n_edges = in_sizes[2];             // 1.6M
    const int nbuck   = (n_nodes + NBNODES - 1) >> NBSH;   // 782
    const int cblocks = (n_edges + CHUNK - 1) / CHUNK;     // 98

    // Workspace (~26.2 MB):
    //   [0, 12.8M): union { pkA int2[E] (dead after fine_sort) ;
    //                       hbf ushort[N*64] (written by linear AFTER fine_sort) }
    //   [12.8M, 25.6M): pkB int2[E]
    //   then offs int[N+1], btot[MAXB], gcur[MAXB], bb[nbuck+1]
    char* ws = (char*)d_ws;
    ushort_t* hbf = (ushort_t*)ws;
    int2*  pkA  = (int2*)ws;
    int2*  pkB  = (int2*)(ws + (size_t)n_edges * sizeof(int2));
    int*   offs = (int*)(pkB + n_edges);
    int*   btot = offs + (n_nodes + 1);
    int*   gcur = btot + MAXB;
    int*   bb   = gcur + MAXB;

    hipMemsetAsync(btot, 0, 2 * MAXB * sizeof(int), stream);  // btot + gcur

    coarse_hist_kernel<<<cblocks, CTHREADS, 0, stream>>>(dst, btot, n_edges, nbuck);
    bucket_scan_kernel<<<1, 1024, 0, stream>>>(btot, bb, nbuck);
    coarse_scatter_kernel<<<cblocks, CTHREADS, 0, stream>>>(src, dst, att, bb,
                                                            gcur, pkA, n_edges, nbuck);
    fine_sort_kernel<<<nbuck, 256, 0, stream>>>(pkA, bb, pkB, offs,
                                                n_nodes, n_edges, nbuck);
    // linear AFTER fine_sort: hbf overwrites the dead pkA region.
    gat_linear_mfma<<<1024, 256, 0, stream>>>(feat, W, bias, hbf, n_nodes);

    const int node_qblocks = (n_nodes * 16 + 255) / 256;
    gat_aggregate_kernel<<<node_qblocks, 256, 0, stream>>>(hbf, offs, pkB, out, n_nodes);
}